// Round 2
// baseline (985.266 us; speedup 1.0000x reference)
//
#include <hip/hip_runtime.h>

// ScaleLasryLions R4: same 4-stage dataflow/layouts as R3, but all transposing
// stores go through LDS so every global store instruction writes complete
// 64-B lines (R3 rocprof: k1 WRITE_SIZE 3x ideal from per-lane 128-B chunks).
//
// K1: x (interleaved) -> H-dil/H-ero, tiled h-fast layout
//     buf[((p*FT+ty)*W + w)*32 + o], tail rows at TAILOFF (unchanged layout).
//     Two 16-row phases per thread (bounded register liveness), each staged
//     to XOR-swizzled LDS then co-op stored lane-fastest (full lines).
// K2: pass1 windows read global h-fast chunks (L1-resident, 16-out chunks),
//     intermediate in LDS tmp[32][P2T]; pass2 -> outb[32][196] -> co-op
//     full-row stores to planar [p][h'][w].
// K3: final H-pass + blend -> res planar (unchanged)
// K4: res planar -> out interleaved (unchanged)

constexpr int BB = 8, HH = 192, WW = 192, CHN = 32, SCST = 128;

constexpr float s2_of(int si) { // scale^2 for {0.25,0.75,1.75,3.75}
    return si == 0 ? 0.0625f : si == 1 ? 0.5625f : si == 2 ? 3.0625f : 14.0625f;
}
constexpr int cdiv_(int a, int b) { return (a + b - 1) / b; }

// ---------------- K1: H-pass, LDS-staged transposed stores ----------------
// MODE: 0 = both (dil->A, ero->Bb), 1 = dil only ->A, 2 = ero only ->A
template <int SI, int SW, int MODE>
__launch_bounds__(256, 4) __global__
void k1_hpass(const float* __restrict__ x, const float* __restrict__ coef,
              float* __restrict__ A, float* __restrict__ Bb) {
    constexpr int L = 2 * SW + 1, HA = HH + 2 * SW, FT = HA / 32, TR = HA - 32 * FT;
    constexpr int WN = 32 + 2 * SW, PW = 16 + 2 * SW;
    constexpr size_t TAILOFF = (size_t)CHN * BB * FT * WW * 32;
    constexpr float S2 = s2_of(SI);
    __shared__ float sd[32 * 8 * 16];
    __shared__ float se[32 * 8 * 16];
    const int tid = threadIdx.x;
    const int c = tid & 31, wl = tid >> 5;        // 32 c x 8 w
    const int w0 = blockIdx.x * 8;
    const int ty = blockIdx.y;
    const int b = blockIdx.z;
    const int r0 = ty * 32;
    const bool tail = (ty == FT);                  // TR>0 for all scales here
    const float kmul = coef[c];

    float wb[WN];
    const float* xb = x + ((size_t)b * HH * WW + (w0 + wl)) * SCST + SI * CHN + c;
#pragma unroll
    for (int t = 0; t < PW; ++t) {
        int gh = r0 + t - 2 * SW;
        gh = gh < 0 ? 0 : (gh > HH - 1 ? HH - 1 : gh);
        wb[t] = xb[(size_t)gh * (WW * SCST)];
    }

    // ---- phase A: outputs o = 0..15 ----
    {
        float ad[16], ae[16];
#pragma unroll
        for (int j = 0; j < L; ++j) {
            const float v = (float)(j - SW);
            const float tp = (-(v * v) / S2) * kmul;
#pragma unroll
            for (int o = 0; o < 16; ++o) {
                float t2 = wb[o + j];
                if (MODE != 2) { float td = t2 + tp; ad[o] = (j == 0) ? td : fmaxf(ad[o], td); }
                if (MODE != 1) { float te = t2 - tp; ae[o] = (j == 0) ? te : fminf(ae[o], te); }
            }
        }
        const int sb = (c * 8 + wl) * 16, xr = 2 * (c & 7);
#pragma unroll
        for (int o = 0; o < 16; ++o) {
            if (MODE != 2) sd[sb + (o ^ xr)] = ad[o];
            if (MODE != 1) se[sb + (o ^ xr)] = ae[o];
        }
    }
    __syncthreads();
    if (!tail) { // co-op store phase A (full lines)
#pragma unroll
        for (int it = 0; it < 4; ++it) {
            int gidx = it * 256 + tid;
            int cc = gidx >> 5, rem = gidx & 31, w = rem >> 2, o4 = rem & 3;
            int xr = 2 * (cc & 7), sb = (cc * 8 + w) * 16;
            size_t ga = (((size_t)(cc * BB + b) * FT + ty) * WW + (w0 + w)) * 32 + o4 * 4;
            if (MODE != 2) {
                float2 a0 = *(const float2*)&sd[sb + ((o4 * 4) ^ xr)];
                float2 a1 = *(const float2*)&sd[sb + ((o4 * 4 + 2) ^ xr)];
                *(float4*)&A[ga] = make_float4(a0.x, a0.y, a1.x, a1.y);
            }
            if (MODE != 1) {
                float2 e0 = *(const float2*)&se[sb + ((o4 * 4) ^ xr)];
                float2 e1 = *(const float2*)&se[sb + ((o4 * 4 + 2) ^ xr)];
                float* dst = (MODE == 0) ? Bb : A;
                *(float4*)&dst[ga] = make_float4(e0.x, e0.y, e1.x, e1.y);
            }
        }
        __syncthreads();
        // ---- phase B: outputs o = 16..31 ----
#pragma unroll
        for (int t = PW; t < WN; ++t) {
            int gh = r0 + t - 2 * SW;
            gh = gh < 0 ? 0 : (gh > HH - 1 ? HH - 1 : gh);
            wb[t] = xb[(size_t)gh * (WW * SCST)];
        }
        {
            float ad[16], ae[16];
#pragma unroll
            for (int j = 0; j < L; ++j) {
                const float v = (float)(j - SW);
                const float tp = (-(v * v) / S2) * kmul;
#pragma unroll
                for (int o = 0; o < 16; ++o) {
                    float t2 = wb[16 + o + j];
                    if (MODE != 2) { float td = t2 + tp; ad[o] = (j == 0) ? td : fmaxf(ad[o], td); }
                    if (MODE != 1) { float te = t2 - tp; ae[o] = (j == 0) ? te : fminf(ae[o], te); }
                }
            }
            const int sb = (c * 8 + wl) * 16, xr = 2 * (c & 7);
#pragma unroll
            for (int o = 0; o < 16; ++o) {
                if (MODE != 2) sd[sb + (o ^ xr)] = ad[o];
                if (MODE != 1) se[sb + (o ^ xr)] = ae[o];
            }
        }
        __syncthreads();
#pragma unroll
        for (int it = 0; it < 4; ++it) { // co-op store phase B
            int gidx = it * 256 + tid;
            int cc = gidx >> 5, rem = gidx & 31, w = rem >> 2, o4 = rem & 3;
            int xr = 2 * (cc & 7), sb = (cc * 8 + w) * 16;
            size_t ga = (((size_t)(cc * BB + b) * FT + ty) * WW + (w0 + w)) * 32 + 16 + o4 * 4;
            if (MODE != 2) {
                float2 a0 = *(const float2*)&sd[sb + ((o4 * 4) ^ xr)];
                float2 a1 = *(const float2*)&sd[sb + ((o4 * 4 + 2) ^ xr)];
                *(float4*)&A[ga] = make_float4(a0.x, a0.y, a1.x, a1.y);
            }
            if (MODE != 1) {
                float2 e0 = *(const float2*)&se[sb + ((o4 * 4) ^ xr)];
                float2 e1 = *(const float2*)&se[sb + ((o4 * 4 + 2) ^ xr)];
                float* dst = (MODE == 0) ? Bb : A;
                *(float4*)&dst[ga] = make_float4(e0.x, e0.y, e1.x, e1.y);
            }
        }
    } else { // tail block: only phase A computed; scalar co-op store of TR rows
#pragma unroll
        for (int it = 0; it < TR; ++it) {
            int gidx = it * 256 + tid;                // 256*TR = 32c*8w*TR exact
            int cc = gidx / (8 * TR);
            int rem = gidx - cc * 8 * TR;
            int w = rem / TR, o = rem - w * TR;
            int xr = 2 * (cc & 7), sb = (cc * 8 + w) * 16;
            size_t ga = TAILOFF + ((size_t)(cc * BB + b) * WW + (w0 + w)) * TR + o;
            if (MODE != 2) A[ga] = sd[sb + (o ^ xr)];
            if (MODE != 1) { float* dst = (MODE == 0) ? Bb : A; dst[ga] = se[sb + (o ^ xr)]; }
        }
    }
}

// ---------------- K2: two W-passes, tiled-transposed in -> planar out ----------
// BR 0 (closing, from dilH): dilW(+k) then eroW(-kc)
// BR 1 (opening, from eroH): eroW(-k) then dilW(+kc)
template <int SI, int SW, int BR>
__launch_bounds__(256, 4) __global__
void k2_wpass(const float* __restrict__ In, const float* __restrict__ coef,
              const float* __restrict__ cin, float* __restrict__ Out) {
    constexpr int L = 2 * SW + 1, HA = HH + 2 * SW, WE = WW + 2 * SW;
    constexpr int FT = HA / 32, TR = HA - 32 * FT;
    constexpr int NQ1 = cdiv_(WE, 8), NQ2 = WW / 8;  // per-thread outputs
    constexpr int P2T = WE + ((4 - (WE & 7) + 8) & 7); // >=WE, ==4 (mod 8)
    constexpr size_t TAILOFF = (size_t)CHN * BB * FT * WW * 32;
    constexpr float S2 = s2_of(SI);
    __shared__ float tmp[32][P2T];
    __shared__ float outb[32][196];
    const int tid = threadIdx.x;
    const int l = tid & 31, g = tid >> 5;            // 32 h-lanes x 8 w-groups
    const int ty = blockIdx.x;
    const int p = blockIdx.y;                         // c*8+b
    const int c = p >> 3;
    const bool tail = (ty == FT);
    const int nr = tail ? TR : 32;
    const int le = (l < nr) ? l : (nr - 1);
    const int pitch = tail ? TR : 32;
    const float* tb = tail ? (In + TAILOFF + (size_t)p * WW * TR)
                           : (In + (((size_t)p * FT + ty) * (size_t)WW) * 32);
    const float k1 = coef[c], k2v = coef[c] * cin[c];

    // pass 1: W (clamp-padded) -> WE, chunks of 16 outputs
#pragma unroll
    for (int cc = 0; cc < 2; ++cc) {
        const int c0 = cc * 16;
        const int q0 = g * NQ1 + c0;
        float wbuf[16 + 2 * SW];
#pragma unroll
        for (int t = 0; t < 16 + 2 * SW; ++t) {
            int wi = q0 + t - 2 * SW;
            wi = wi < 0 ? 0 : (wi > WW - 1 ? WW - 1 : wi);
            wbuf[t] = tb[wi * pitch + le];
        }
        float acc[16];
#pragma unroll
        for (int j = 0; j < L; ++j) {
            const float v = (float)(j - SW);
            const float tp = (-(v * v) / S2) * k1;
#pragma unroll
            for (int o = 0; o < 16; ++o) {
                float t2 = (BR == 0) ? wbuf[o + j] + tp : wbuf[o + j] - tp;
                acc[o] = (j == 0) ? t2 : ((BR == 0) ? fmaxf(acc[o], t2) : fminf(acc[o], t2));
            }
        }
#pragma unroll
        for (int o = 0; o < 16; ++o) {
            int q = q0 + o;
            if (c0 + o < NQ1 && q < WE) tmp[l][q] = acc[o];
        }
    }
    __syncthreads();
    // pass 2: WE -> W (VALID), opposite op, taps kc, chunks of 16
#pragma unroll
    for (int cc = 0; cc < 2; ++cc) {
        const int c0 = cc * 16;
        const int q0 = g * NQ2 + c0;
        float wbuf[16 + 2 * SW];
#pragma unroll
        for (int t = 0; t < 16 + 2 * SW; ++t) {
            int qi = q0 + t;
            qi = qi < WE - 1 ? qi : WE - 1;
            wbuf[t] = tmp[l][qi];
        }
        float acc[16];
#pragma unroll
        for (int j = 0; j < L; ++j) {
            const float v = (float)(j - SW);
            const float tp = (-(v * v) / S2) * k2v;
#pragma unroll
            for (int o = 0; o < 16; ++o) {
                float t2 = (BR == 0) ? wbuf[o + j] - tp : wbuf[o + j] + tp;
                acc[o] = (j == 0) ? t2 : ((BR == 0) ? fminf(acc[o], t2) : fmaxf(acc[o], t2));
            }
        }
#pragma unroll
        for (int o = 0; o < 16; ++o)
            if (c0 + o < NQ2) outb[l][q0 + o] = acc[o];
    }
    __syncthreads();
    // co-op full-row stores (complete lines)
#pragma unroll
    for (int it = 0; it < 6; ++it) {
        int gidx = it * 256 + tid;
        int r = gidx / 48, q4 = gidx - r * 48;
        if (r < nr) {
            float4 vv = *(const float4*)&outb[r][q4 * 4];
            *(float4*)&Out[((size_t)p * HA + (size_t)ty * 32 + r) * WW + q4 * 4] = vv;
        }
    }
}

// ---------------- K3: final H-pass + blend -> res planar ----------------
// MODE 0: fused; MODE 1: res = av*eroH(A); MODE 2: res += (1-av)*dilH(B)
template <int SI, int SW, int MODE>
__launch_bounds__(256, 4) __global__
void k3_hpass(const float* __restrict__ A, const float* __restrict__ Bb,
              const float* __restrict__ coef, const float* __restrict__ cin,
              const float* __restrict__ ain, float* __restrict__ res) {
    constexpr int L = 2 * SW + 1, HA = HH + 2 * SW, RS = 64, RT = RS + 2 * SW;
    constexpr float S2 = s2_of(SI);
    __shared__ float tile[RT][64 + 1];
    const int tid = threadIdx.x;
    const int p = blockIdx.z;            // plane = c*8+b
    const int c = p >> 3;
    const int w0 = blockIdx.x * 64, r0 = blockIdx.y * RS;
    const float kc = coef[c] * cin[c], av = ain[c];
    const int wl = tid & 63, rq = tid >> 6; // 4 groups x 16 rows

    float xc[16];
    if (MODE != 2) {
        const float* Ab = A + ((size_t)p * HA + r0) * WW + w0;
        for (int i = tid; i < RT * 64; i += 256) {
            int r = i >> 6, w2 = i & 63;
            tile[r][w2] = Ab[(size_t)r * WW + w2];
        }
        __syncthreads();
        float wbuf[16 + 2 * SW];
#pragma unroll
        for (int t = 0; t < 16 + 2 * SW; ++t) wbuf[t] = tile[rq * 16 + t][wl];
#pragma unroll
        for (int j = 0; j < L; ++j) {
            const float v = (float)(j - SW);
            const float tp = (-(v * v) / S2) * kc;
#pragma unroll
            for (int o = 0; o < 16; ++o) {
                float t2 = wbuf[o + j] - tp; // erosion
                xc[o] = (j == 0) ? t2 : fminf(xc[o], t2);
            }
        }
        if (MODE == 0) __syncthreads();
    }
    float xo[16];
    if (MODE != 1) {
        const float* Bp = Bb + ((size_t)p * HA + r0) * WW + w0;
        for (int i = tid; i < RT * 64; i += 256) {
            int r = i >> 6, w2 = i & 63;
            tile[r][w2] = Bp[(size_t)r * WW + w2];
        }
        __syncthreads();
        float wbuf[16 + 2 * SW];
#pragma unroll
        for (int t = 0; t < 16 + 2 * SW; ++t) wbuf[t] = tile[rq * 16 + t][wl];
#pragma unroll
        for (int j = 0; j < L; ++j) {
            const float v = (float)(j - SW);
            const float tp = (-(v * v) / S2) * kc;
#pragma unroll
            for (int o = 0; o < 16; ++o) {
                float t2 = wbuf[o + j] + tp; // dilation
                xo[o] = (j == 0) ? t2 : fmaxf(xo[o], t2);
            }
        }
    }
    float* rp = res + ((size_t)p * HH + r0) * WW + w0;
#pragma unroll
    for (int o = 0; o < 16; ++o) {
        size_t idx = (size_t)(rq * 16 + o) * WW + wl;
        if (MODE == 0)      rp[idx] = av * xc[o] + (1.0f - av) * xo[o];
        else if (MODE == 1) rp[idx] = av * xc[o];
        else                rp[idx] = rp[idx] + (1.0f - av) * xo[o];
    }
}

// ---------------- K4: planar res -> interleaved out ----------------
template <int SI>
__launch_bounds__(256, 8) __global__
void k_scatter(const float* __restrict__ res, float* __restrict__ out) {
    __shared__ float stg[CHN][33];
    const int tid = threadIdx.x;
    const int w0 = blockIdx.x * 32, h = blockIdx.y, b = blockIdx.z;
#pragma unroll
    for (int it = 0; it < 4; ++it) {
        int cc = (tid >> 5) + it * 8, w = tid & 31;
        stg[cc][w] = res[((size_t)(cc * BB + b) * HH + h) * WW + w0 + w];
    }
    __syncthreads();
#pragma unroll
    for (int it = 0; it < 4; ++it) {
        int w = (tid >> 5) + it * 8, cc = tid & 31;
        out[((size_t)(b * HH + h) * WW + w0 + w) * SCST + SI * CHN + cc] = stg[cc][w];
    }
}

// ---------------- Fallback: fused kernel (used if ws too small) ----------------
constexpr int r4_(int a) { return (a + 3) & ~3; }
constexpr int pickNH(int R, int C, int NT) {
    for (int nh = 1; nh <= R; ++nh)
        if (cdiv_(R, nh) * C <= NT) return nh;
    return R;
}
template <int L, int SW, int SI, bool DIL, int NH, int R, int PIT>
__device__ __forceinline__ void pass_compute_si(const float* __restrict__ in, int r0, int c,
                                                float kmul, float (&acc)[NH]) {
    constexpr float S2 = s2_of(SI);
    float wb[NH + L - 1];
#pragma unroll
    for (int t = 0; t < NH + L - 1; ++t) {
        int rr = r0 + t;
        if (rr > R + L - 2) rr = R + L - 2;
        wb[t] = in[rr * PIT + c];
    }
#pragma unroll
    for (int j = 0; j < L; ++j) {
        float v = (float)(j - SW);
        float tp = (-(v * v) / S2) * kmul;
#pragma unroll
        for (int o = 0; o < NH; ++o) {
            float t = DIL ? wb[o + j] + tp : wb[o + j] - tp;
            if (j == 0) acc[o] = t;
            else acc[o] = DIL ? fmaxf(acc[o], t) : fminf(acc[o], t);
        }
    }
}
template <int L, int SW, int SI, bool DIL, int NH, int R, int C, int PIT, int POUT, int NT>
__device__ __forceinline__ void pass_lds(const float* __restrict__ in, float* __restrict__ outT,
                                         float kmul, int tid) {
    constexpr int nseg = cdiv_(R, NH);
    for (int item = tid; item < nseg * C; item += NT) {
        int c = item % C, r0 = (item / C) * NH;
        float acc[NH];
        pass_compute_si<L, SW, SI, DIL, NH, R, PIT>(in, r0, c, kmul, acc);
#pragma unroll
        for (int o = 0; o < NH; ++o)
            if (r0 + o < R) outT[c * POUT + (r0 + o)] = acc[o];
    }
}
template <int SI, int SW, int TH, int TW, int NT, int MW>
__launch_bounds__(NT, MW) __global__
void lasry_kernel(const float* __restrict__ x, const float* __restrict__ coef,
                  const float* __restrict__ cin, const float* __restrict__ ain,
                  float* __restrict__ out) {
    constexpr int L = 2 * SW + 1;
    constexpr int IH = TH + 4 * SW, IW = TW + 4 * SW;
    constexpr int R1 = TH + 2 * SW, C1 = IW;
    constexpr int R2 = TW + 2 * SW, C2 = R1;
    constexpr int R3 = TH,          C3 = R2;
    constexpr int R4 = TW,          C4 = R3;
    constexpr int PIN = IW, PA = r4_(R1), PB = r4_(R2), PA2 = r4_(R3);
    constexpr int NH1 = pickNH(R1, C1, NT), NH2 = pickNH(R2, C2, NT);
    constexpr int NH3 = pickNH(R3, C3, NT), NH4 = pickNH(R4, C4, NT);
    __shared__ float smem[IH * PIN + C1 * PA + C2 * PB];
    float* bufIn = smem;
    float* A = smem + IH * PIN;
    float* B = A + C1 * PA;
    float* A2 = A;
    const int tid = threadIdx.x;
    const int b = blockIdx.z >> 5, ch = blockIdx.z & 31;
    const int h0 = blockIdx.y * TH, w0 = blockIdx.x * TW;
    const float kmul = coef[ch];
    const float kcmul = kmul * cin[ch];
    const float av = ain[ch];
    const float* xb = x + (size_t)(b * HH * WW) * SCST + SI * CHN + ch;
    constexpr int NLOAD = cdiv_(IH * IW, NT);
#pragma unroll
    for (int t = 0; t < NLOAD; ++t) {
        int idx = tid + t * NT;
        if (idx < IH * IW) {
            int r = idx / IW, c = idx - r * IW;
            int gh = min(max(h0 + r - 2 * SW, 0), HH - 1);
            int gw = min(max(w0 + c - 2 * SW, 0), WW - 1);
            bufIn[r * PIN + c] = xb[(size_t)(gh * WW + gw) * SCST];
        }
    }
    __syncthreads();
    const int c4 = tid % C4;
    const int r04 = (tid / C4) * NH4;
    const bool act4 = tid < cdiv_(R4, NH4) * C4;
    float xcv[NH4];
    pass_lds<L, SW, SI, true,  NH1, R1, C1, PIN, PA,  NT>(bufIn, A, kmul, tid);  __syncthreads();
    pass_lds<L, SW, SI, true,  NH2, R2, C2, PA,  PB,  NT>(A,     B, kmul, tid);  __syncthreads();
    pass_lds<L, SW, SI, false, NH3, R3, C3, PB,  PA2, NT>(B,    A2, kcmul, tid); __syncthreads();
    if (act4) pass_compute_si<L, SW, SI, false, NH4, R4, PA2>(A2, r04, c4, kcmul, xcv);
    __syncthreads();
    pass_lds<L, SW, SI, false, NH1, R1, C1, PIN, PA,  NT>(bufIn, A, kmul, tid);  __syncthreads();
    pass_lds<L, SW, SI, false, NH2, R2, C2, PA,  PB,  NT>(A,     B, kmul, tid);  __syncthreads();
    pass_lds<L, SW, SI, true,  NH3, R3, C3, PB,  PA2, NT>(B,    A2, kcmul, tid); __syncthreads();
    if (act4) {
        float xov[NH4];
        pass_compute_si<L, SW, SI, true, NH4, R4, PA2>(A2, r04, c4, kcmul, xov);
        const int h = h0 + c4;
        float* ob = out + ((size_t)(b * HH + h) * WW) * SCST + SI * CHN + ch;
#pragma unroll
        for (int o = 0; o < NH4; ++o) {
            int w = w0 + r04 + o;
            if (r04 + o < R4 && w < WW) ob[(size_t)w * SCST] = av * xcv[o] + (1.0f - av) * xov[o];
        }
    }
}

// ---------------- host ----------------
template <int SI, int SW>
static void run_t1(const float* x, const float* coef, const float* cv, const float* av,
                   float* out, float* At, float* Bt, float* A2, float* B2, float* res,
                   hipStream_t s) {
    constexpr int HA = HH + 2 * SW, FT = HA / 32, TR = HA - 32 * FT, NT = FT + (TR ? 1 : 0);
    k1_hpass<SI, SW, 0><<<dim3(WW / 8, NT, BB), 256, 0, s>>>(x, coef, At, Bt);
    k2_wpass<SI, SW, 0><<<dim3(NT, CHN * BB), 256, 0, s>>>(At, coef, cv, A2);
    k2_wpass<SI, SW, 1><<<dim3(NT, CHN * BB), 256, 0, s>>>(Bt, coef, cv, B2);
    k3_hpass<SI, SW, 0><<<dim3(WW / 64, HH / 64, CHN * BB), 256, 0, s>>>(A2, B2, coef, cv, av, res);
    k_scatter<SI><<<dim3(WW / 32, HH, BB), 256, 0, s>>>(res, out);
}
template <int SI, int SW>
static void run_t2(const float* x, const float* coef, const float* cv, const float* av,
                   float* out, float* R1, float* R2, float* res, hipStream_t s) {
    constexpr int HA = HH + 2 * SW, FT = HA / 32, TR = HA - 32 * FT, NT = FT + (TR ? 1 : 0);
    k1_hpass<SI, SW, 1><<<dim3(WW / 8, NT, BB), 256, 0, s>>>(x, coef, R1, nullptr);
    k2_wpass<SI, SW, 0><<<dim3(NT, CHN * BB), 256, 0, s>>>(R1, coef, cv, R2);
    k3_hpass<SI, SW, 1><<<dim3(WW / 64, HH / 64, CHN * BB), 256, 0, s>>>(R2, R2, coef, cv, av, res);
    k1_hpass<SI, SW, 2><<<dim3(WW / 8, NT, BB), 256, 0, s>>>(x, coef, R1, nullptr);
    k2_wpass<SI, SW, 1><<<dim3(NT, CHN * BB), 256, 0, s>>>(R1, coef, cv, R2);
    k3_hpass<SI, SW, 2><<<dim3(WW / 64, HH / 64, CHN * BB), 256, 0, s>>>(R2, R2, coef, cv, av, res);
    k_scatter<SI><<<dim3(WW / 32, HH, BB), 256, 0, s>>>(res, out);
}

extern "C" void kernel_launch(void* const* d_in, const int* in_sizes, int n_in,
                              void* d_out, int out_size, void* d_ws, size_t ws_size,
                              hipStream_t stream) {
    const float* x    = (const float*)d_in[0];
    const float* coef = (const float*)d_in[1];
    const float* cv   = (const float*)d_in[2];
    const float* av   = (const float*)d_in[3];
    float* out = (float*)d_out;
    (void)in_sizes; (void)n_in; (void)out_size;

    constexpr size_t TBUF  = (size_t)CHN * BB * (HH + 2 * 18) * WW;   // 11,206,656 floats (SI3 size)
    constexpr size_t RESSZ = (size_t)CHN * BB * HH * WW;              //  9,437,184 floats
    constexpr size_t T1_NEED = 3 * TBUF * sizeof(float);              // 134,479,872 B
    constexpr size_t T2_NEED = (2 * TBUF + RESSZ) * sizeof(float);    // 127,401,984 B

    float* W0 = (float*)d_ws;
    if (ws_size >= T1_NEED) {
        float* At = W0;
        float* Bt = W0 + TBUF;
        float* A2 = W0 + 2 * TBUF;
        float* B2 = W0;          // reuse At region (dead after k2a)
        float* res = W0 + TBUF;  // reuse Bt region (dead after k2b)
        run_t1<0, 1>(x, coef, cv, av, out, At, Bt, A2, B2, res, stream);
        run_t1<1, 3>(x, coef, cv, av, out, At, Bt, A2, B2, res, stream);
        run_t1<2, 8>(x, coef, cv, av, out, At, Bt, A2, B2, res, stream);
        run_t1<3, 18>(x, coef, cv, av, out, At, Bt, A2, B2, res, stream);
    } else if (ws_size >= T2_NEED) {
        float* R1 = W0;
        float* R2 = W0 + TBUF;
        float* res = W0 + 2 * TBUF;
        run_t2<0, 1>(x, coef, cv, av, out, R1, R2, res, stream);
        run_t2<1, 3>(x, coef, cv, av, out, R1, R2, res, stream);
        run_t2<2, 8>(x, coef, cv, av, out, R1, R2, res, stream);
        run_t2<3, 18>(x, coef, cv, av, out, R1, R2, res, stream);
    } else {
        lasry_kernel<0, 1, 64, 64, 1024, 8><<<dim3(3, 3, 256), 1024, 0, stream>>>(x, coef, cv, av, out);
        lasry_kernel<1, 3, 64, 64, 1024, 8><<<dim3(3, 3, 256), 1024, 0, stream>>>(x, coef, cv, av, out);
        lasry_kernel<2, 8, 64, 64, 1024, 4><<<dim3(3, 3, 256), 1024, 0, stream>>>(x, coef, cv, av, out);
        lasry_kernel<3, 18, 64, 48, 1024, 4><<<dim3(4, 3, 256), 1024, 0, stream>>>(x, coef, cv, av, out);
    }
}

// Round 4
// 933.679 us; speedup vs baseline: 1.0553x; 1.0553x over previous
//
#include <hip/hip_runtime.h>

// ScaleLasryLions R5b: reorder separable morphology so NO transposed (h-fast)
// global layout exists. closing = eroW(eroH(dilH(dilW x))), opening =
// dilW(dilH(eroH(eroW x))) (same-type passes commute exactly).
// Per scale, per h-half (96 rows), per branch:
//   K1: W-pass from x (row-resident in LDS), planar out [p][r][w] pitch16
//   K2: fused H-pass pair (dilH+eroH / eroH+dilH), column stripes of 16 w
//   K3: final W-pass both branches + blend + direct interleaved scatter
//       (single 29KB LDS buffer, serial HC->HO processing)
// All global reads/writes are w-fast coalesced full lines. Workspace:
// W1 (41.3MB) + HC + HO (23.6MB each) = 88.5MB.

constexpr int BB = 8, HH = 192, WW = 192, CHN = 32, SCST = 128;
constexpr int HHF = 96; // h-half

constexpr float s2_of(int si) { // scale^2 for {0.25,0.75,1.75,3.75}
    return si == 0 ? 0.0625f : si == 1 ? 0.5625f : si == 2 ? 3.0625f : 14.0625f;
}
constexpr int cdiv_(int a, int b) { return (a + b - 1) / b; }
constexpr int r16_(int a) { return (a + 15) & ~15; }

// ---------------- K1: W-pass (one branch) ----------------
// ERO=0: dilation (+tap, max); ERO=1: erosion (-tap, min). Taps k.
// Output rows r in [0,RIN) map to padded-h = h0-2SW+r (clamped source).
template <int SI, int SW, int ERO>
__launch_bounds__(256, 3) __global__
void k1_w(const float* __restrict__ x, const float* __restrict__ coef,
          float* __restrict__ W1, int h0) {
    constexpr int L = 2 * SW + 1, WIN = WW + 4 * SW, OW = WW + 2 * SW;
    constexpr int PITCH = r16_(OW), RIN = HHF + 4 * SW;
    constexpr int PIN = WIN + 1, PST = OW + 1;
    constexpr int CE = cdiv_(OW, 8);
    constexpr float S2 = s2_of(SI);
    __shared__ float sm[32 * PIN];
    const int tid = threadIdx.x;
    const int r = blockIdx.x, b = blockIdx.y;
    int gh = h0 - 2 * SW + r;
    gh = gh < 0 ? 0 : (gh > HH - 1 ? HH - 1 : gh);
    // load row window: lanes sweep c (128B chunks), w outer
    for (int idx = tid; idx < 32 * WIN; idx += 256) {
        int c = idx & 31, w = idx >> 5;
        int gw = w - 2 * SW;
        gw = gw < 0 ? 0 : (gw > WW - 1 ? WW - 1 : gw);
        sm[c * PIN + w] = x[((size_t)(b * HH + gh) * WW + gw) * SCST + SI * CHN + c];
    }
    __syncthreads();
    const int c = tid & 31, g = tid >> 5;
    const float km = coef[c];
    float acc[CE];
    {
        float wbuf[CE + 2 * SW];
#pragma unroll
        for (int t = 0; t < CE + 2 * SW; ++t) {
            int wi = g * CE + t;
            wi = wi < WIN ? wi : WIN - 1;
            wbuf[t] = sm[c * PIN + wi];
        }
#pragma unroll
        for (int j = 0; j < L; ++j) {
            const float v = (float)(j - SW);
            const float tp = (-(v * v) / S2) * km;
#pragma unroll
            for (int o = 0; o < CE; ++o) {
                float t2 = ERO ? wbuf[o + j] - tp : wbuf[o + j] + tp;
                acc[o] = (j == 0) ? t2 : (ERO ? fminf(acc[o], t2) : fmaxf(acc[o], t2));
            }
        }
    }
    __syncthreads();
#pragma unroll
    for (int o = 0; o < CE; ++o) {
        int w = g * CE + o;
        if (w < OW) sm[c * PST + w] = acc[o];
    }
    __syncthreads();
    // co-op planar row stores (w-fast, full lines)
    for (int idx = tid; idx < 32 * OW; idx += 256) {
        int cc = idx / OW, w = idx - cc * OW;
        W1[((size_t)(cc * BB + b) * RIN + r) * PITCH + w] = sm[cc * PST + w];
    }
}

// ---------------- K2: fused H-pass pair, 16-w column stripes ----------------
// BR=0 (closing): dilH(+k,max) then eroH(-kc,min)
// BR=1 (opening): eroH(-k,min) then dilH(+kc,max)
template <int SI, int SW, int BR>
__launch_bounds__(256, 4) __global__
void k2_h(const float* __restrict__ W1, const float* __restrict__ coef,
          const float* __restrict__ cv, float* __restrict__ Hout) {
    constexpr int L = 2 * SW + 1, OW = WW + 2 * SW, PITCH = r16_(OW);
    constexpr int RIN = HHF + 4 * SW, RD = HHF + 2 * SW;
    constexpr int CH1 = cdiv_(RD, 16), CH2 = HHF / 16; // 16 row-groups
    constexpr float S2 = s2_of(SI);
    __shared__ float tin[RIN * 17];
    __shared__ float tdil[RD * 17];
    const int tid = threadIdx.x;
    const int st = blockIdx.x, p = blockIdx.y, c = p >> 3;
    const float k1 = coef[c], k2 = coef[c] * cv[c];
    const float* wrow = W1 + (size_t)p * RIN * PITCH + st * 16;
    for (int idx = tid; idx < RIN * 16; idx += 256) {
        int r = idx >> 4, w = idx & 15;
        tin[r * 17 + w] = wrow[(size_t)r * PITCH + w];
    }
    __syncthreads();
    const int w = tid & 15, rg = tid >> 4;
    { // phase 1: taps k
        float wbuf[CH1 + 2 * SW];
#pragma unroll
        for (int t = 0; t < CH1 + 2 * SW; ++t) {
            int ri = rg * CH1 + t;
            ri = ri < RIN ? ri : RIN - 1;
            wbuf[t] = tin[ri * 17 + w];
        }
        float acc[CH1];
#pragma unroll
        for (int j = 0; j < L; ++j) {
            const float v = (float)(j - SW);
            const float tp = (-(v * v) / S2) * k1;
#pragma unroll
            for (int o = 0; o < CH1; ++o) {
                float t2 = BR ? wbuf[o + j] - tp : wbuf[o + j] + tp;
                acc[o] = (j == 0) ? t2 : (BR ? fminf(acc[o], t2) : fmaxf(acc[o], t2));
            }
        }
#pragma unroll
        for (int o = 0; o < CH1; ++o) {
            int d = rg * CH1 + o;
            if (d < RD) tdil[d * 17 + w] = acc[o];
        }
    }
    __syncthreads();
    { // phase 2: taps kc, opposite op
        float wbuf[CH2 + 2 * SW];
#pragma unroll
        for (int t = 0; t < CH2 + 2 * SW; ++t) wbuf[t] = tdil[(rg * CH2 + t) * 17 + w];
        float acc[CH2];
#pragma unroll
        for (int j = 0; j < L; ++j) {
            const float v = (float)(j - SW);
            const float tp = (-(v * v) / S2) * k2;
#pragma unroll
            for (int o = 0; o < CH2; ++o) {
                float t2 = BR ? wbuf[o + j] + tp : wbuf[o + j] - tp;
                acc[o] = (j == 0) ? t2 : (BR ? fmaxf(acc[o], t2) : fminf(acc[o], t2));
            }
        }
        float* orow = Hout + (size_t)p * HHF * PITCH + st * 16;
#pragma unroll
        for (int o = 0; o < CH2; ++o) orow[(size_t)(rg * CH2 + o) * PITCH + w] = acc[o];
    }
}

// ---------------- K3: final W-pass + blend + interleaved scatter ----------------
// Single LDS buffer (29KB): load HC -> xc, reload HO -> xo, blend, stage, scatter.
template <int SI, int SW>
__launch_bounds__(256, 4) __global__
void k3_blend(const float* __restrict__ HC, const float* __restrict__ HO,
              const float* __restrict__ coef, const float* __restrict__ cv,
              const float* __restrict__ ain, float* __restrict__ out, int h0) {
    constexpr int L = 2 * SW + 1, OW = WW + 2 * SW, PITCH = r16_(OW), PB = OW + 1;
    constexpr float S2 = s2_of(SI);
    __shared__ float sm[32 * PB];
    const int tid = threadIdx.x;
    const int hr = blockIdx.x, b = blockIdx.y;
    const int c = tid & 31, g = tid >> 5;
    const float kc = coef[c] * cv[c], av = ain[c];

    // ---- closing tail: erosion over HC ----
    for (int idx = tid; idx < 32 * OW; idx += 256) {
        int cc = idx / OW, w2 = idx - cc * OW;
        sm[cc * PB + w2] = HC[((size_t)(cc * BB + b) * HHF + hr) * PITCH + w2];
    }
    __syncthreads();
    float xcv[24];
#pragma unroll
    for (int ch = 0; ch < 2; ++ch) {
        const int base = g * 24 + ch * 12;
        float wbuf[12 + 2 * SW];
#pragma unroll
        for (int t = 0; t < 12 + 2 * SW; ++t) wbuf[t] = sm[c * PB + base + t];
#pragma unroll
        for (int j = 0; j < L; ++j) {
            const float v = (float)(j - SW);
            const float tp = (-(v * v) / S2) * kc;
#pragma unroll
            for (int o = 0; o < 12; ++o) {
                float t2 = wbuf[o + j] - tp; // erosion
                float& d = xcv[ch * 12 + o];
                d = (j == 0) ? t2 : fminf(d, t2);
            }
        }
    }
    __syncthreads();
    // ---- opening tail: dilation over HO, blend ----
    for (int idx = tid; idx < 32 * OW; idx += 256) {
        int cc = idx / OW, w2 = idx - cc * OW;
        sm[cc * PB + w2] = HO[((size_t)(cc * BB + b) * HHF + hr) * PITCH + w2];
    }
    __syncthreads();
    float bl[24];
#pragma unroll
    for (int ch = 0; ch < 2; ++ch) {
        const int base = g * 24 + ch * 12;
        float wbuf[12 + 2 * SW];
#pragma unroll
        for (int t = 0; t < 12 + 2 * SW; ++t) wbuf[t] = sm[c * PB + base + t];
        float xo[12];
#pragma unroll
        for (int j = 0; j < L; ++j) {
            const float v = (float)(j - SW);
            const float tp = (-(v * v) / S2) * kc;
#pragma unroll
            for (int o = 0; o < 12; ++o) {
                float t2 = wbuf[o + j] + tp; // dilation
                xo[o] = (j == 0) ? t2 : fmaxf(xo[o], t2);
            }
        }
#pragma unroll
        for (int o = 0; o < 12; ++o)
            bl[ch * 12 + o] = av * xcv[ch * 12 + o] + (1.0f - av) * xo[o];
    }
    __syncthreads();
#pragma unroll
    for (int o = 0; o < 24; ++o) sm[c * 193 + g * 24 + o] = bl[o];
    __syncthreads();
    const int habs = h0 + hr;
    for (int idx = tid; idx < WW * 32; idx += 256) {
        int w2 = idx >> 5, cc = idx & 31;
        out[((size_t)(b * HH + habs) * WW + w2) * SCST + SI * CHN + cc] = sm[cc * 193 + w2];
    }
}

// ---------------- Fallback: fused kernel (used if ws too small) ----------------
constexpr int r4_(int a) { return (a + 3) & ~3; }
constexpr int pickNH(int R, int C, int NT) {
    for (int nh = 1; nh <= R; ++nh)
        if (cdiv_(R, nh) * C <= NT) return nh;
    return R;
}
template <int L, int SW, int SI, bool DIL, int NH, int R, int PIT>
__device__ __forceinline__ void pass_compute_si(const float* __restrict__ in, int r0, int c,
                                                float kmul, float (&acc)[NH]) {
    constexpr float S2 = s2_of(SI);
    float wb[NH + L - 1];
#pragma unroll
    for (int t = 0; t < NH + L - 1; ++t) {
        int rr = r0 + t;
        if (rr > R + L - 2) rr = R + L - 2;
        wb[t] = in[rr * PIT + c];
    }
#pragma unroll
    for (int j = 0; j < L; ++j) {
        float v = (float)(j - SW);
        float tp = (-(v * v) / S2) * kmul;
#pragma unroll
        for (int o = 0; o < NH; ++o) {
            float t = DIL ? wb[o + j] + tp : wb[o + j] - tp;
            if (j == 0) acc[o] = t;
            else acc[o] = DIL ? fmaxf(acc[o], t) : fminf(acc[o], t);
        }
    }
}
template <int L, int SW, int SI, bool DIL, int NH, int R, int C, int PIT, int POUT, int NT>
__device__ __forceinline__ void pass_lds(const float* __restrict__ in, float* __restrict__ outT,
                                         float kmul, int tid) {
    constexpr int nseg = cdiv_(R, NH);
    for (int item = tid; item < nseg * C; item += NT) {
        int c = item % C, r0 = (item / C) * NH;
        float acc[NH];
        pass_compute_si<L, SW, SI, DIL, NH, R, PIT>(in, r0, c, kmul, acc);
#pragma unroll
        for (int o = 0; o < NH; ++o)
            if (r0 + o < R) outT[c * POUT + (r0 + o)] = acc[o];
    }
}
template <int SI, int SW, int TH, int TW, int NT, int MW>
__launch_bounds__(NT, MW) __global__
void lasry_kernel(const float* __restrict__ x, const float* __restrict__ coef,
                  const float* __restrict__ cin, const float* __restrict__ ain,
                  float* __restrict__ out) {
    constexpr int L = 2 * SW + 1;
    constexpr int IH = TH + 4 * SW, IW = TW + 4 * SW;
    constexpr int R1 = TH + 2 * SW, C1 = IW;
    constexpr int R2 = TW + 2 * SW, C2 = R1;
    constexpr int R3 = TH,          C3 = R2;
    constexpr int R4 = TW,          C4 = R3;
    constexpr int PIN = IW, PA = r4_(R1), PB = r4_(R2), PA2 = r4_(R3);
    constexpr int NH1 = pickNH(R1, C1, NT), NH2 = pickNH(R2, C2, NT);
    constexpr int NH3 = pickNH(R3, C3, NT), NH4 = pickNH(R4, C4, NT);
    __shared__ float smem[IH * PIN + C1 * PA + C2 * PB];
    float* bufIn = smem;
    float* A = smem + IH * PIN;
    float* B = A + C1 * PA;
    float* A2 = A;
    const int tid = threadIdx.x;
    const int b = blockIdx.z >> 5, ch = blockIdx.z & 31;
    const int h0 = blockIdx.y * TH, w0 = blockIdx.x * TW;
    const float kmul = coef[ch];
    const float kcmul = kmul * cin[ch];
    const float av = ain[ch];
    const float* xb = x + (size_t)(b * HH * WW) * SCST + SI * CHN + ch;
    constexpr int NLOAD = cdiv_(IH * IW, NT);
#pragma unroll
    for (int t = 0; t < NLOAD; ++t) {
        int idx = tid + t * NT;
        if (idx < IH * IW) {
            int r = idx / IW, c = idx - r * IW;
            int gh = min(max(h0 + r - 2 * SW, 0), HH - 1);
            int gw = min(max(w0 + c - 2 * SW, 0), WW - 1);
            bufIn[r * PIN + c] = xb[(size_t)(gh * WW + gw) * SCST];
        }
    }
    __syncthreads();
    const int c4 = tid % C4;
    const int r04 = (tid / C4) * NH4;
    const bool act4 = tid < cdiv_(R4, NH4) * C4;
    float xcv[NH4];
    pass_lds<L, SW, SI, true,  NH1, R1, C1, PIN, PA,  NT>(bufIn, A, kmul, tid);  __syncthreads();
    pass_lds<L, SW, SI, true,  NH2, R2, C2, PA,  PB,  NT>(A,     B, kmul, tid);  __syncthreads();
    pass_lds<L, SW, SI, false, NH3, R3, C3, PB,  PA2, NT>(B,    A2, kcmul, tid); __syncthreads();
    if (act4) pass_compute_si<L, SW, SI, false, NH4, R4, PA2>(A2, r04, c4, kcmul, xcv);
    __syncthreads();
    pass_lds<L, SW, SI, false, NH1, R1, C1, PIN, PA,  NT>(bufIn, A, kmul, tid);  __syncthreads();
    pass_lds<L, SW, SI, false, NH2, R2, C2, PA,  PB,  NT>(A,     B, kmul, tid);  __syncthreads();
    pass_lds<L, SW, SI, true,  NH3, R3, C3, PB,  PA2, NT>(B,    A2, kcmul, tid); __syncthreads();
    if (act4) {
        float xov[NH4];
        pass_compute_si<L, SW, SI, true, NH4, R4, PA2>(A2, r04, c4, kcmul, xov);
        const int h = h0 + c4;
        float* ob = out + ((size_t)(b * HH + h) * WW) * SCST + SI * CHN + ch;
#pragma unroll
        for (int o = 0; o < NH4; ++o) {
            int w = w0 + r04 + o;
            if (r04 + o < R4 && w < WW) ob[(size_t)w * SCST] = av * xcv[o] + (1.0f - av) * xov[o];
        }
    }
}

// ---------------- host ----------------
template <int SI, int SW>
static void run_scale(const float* x, const float* coef, const float* cv, const float* av,
                      float* out, float* W1, float* HC, float* HO, hipStream_t s) {
    constexpr int OW = WW + 2 * SW, PITCH = r16_(OW);
    constexpr int RIN = HHF + 4 * SW, NST = PITCH / 16;
    for (int h0 = 0; h0 < HH; h0 += HHF) {
        k1_w<SI, SW, 0><<<dim3(RIN, BB), 256, 0, s>>>(x, coef, W1, h0);
        k2_h<SI, SW, 0><<<dim3(NST, CHN * BB), 256, 0, s>>>(W1, coef, cv, HC);
        k1_w<SI, SW, 1><<<dim3(RIN, BB), 256, 0, s>>>(x, coef, W1, h0);
        k2_h<SI, SW, 1><<<dim3(NST, CHN * BB), 256, 0, s>>>(W1, coef, cv, HO);
        k3_blend<SI, SW><<<dim3(HHF, BB), 256, 0, s>>>(HC, HO, coef, cv, av, out, h0);
    }
}

extern "C" void kernel_launch(void* const* d_in, const int* in_sizes, int n_in,
                              void* d_out, int out_size, void* d_ws, size_t ws_size,
                              hipStream_t stream) {
    const float* x    = (const float*)d_in[0];
    const float* coef = (const float*)d_in[1];
    const float* cv   = (const float*)d_in[2];
    const float* av   = (const float*)d_in[3];
    float* out = (float*)d_out;
    (void)in_sizes; (void)n_in; (void)out_size;

    // SI3 (max) buffer sizes
    constexpr size_t W1SZ = (size_t)CHN * BB * (HHF + 4 * 18) * 240; // 10,321,920 floats
    constexpr size_t HSZ  = (size_t)CHN * BB * HHF * 240;           //  5,898,240 floats
    constexpr size_t NEED = (W1SZ + 2 * HSZ) * sizeof(float);       // 88,473,600 B

    if (ws_size >= NEED) {
        float* W1 = (float*)d_ws;
        float* HC = W1 + W1SZ;
        float* HO = HC + HSZ;
        run_scale<0, 1>(x, coef, cv, av, out, W1, HC, HO, stream);
        run_scale<1, 3>(x, coef, cv, av, out, W1, HC, HO, stream);
        run_scale<2, 8>(x, coef, cv, av, out, W1, HC, HO, stream);
        run_scale<3, 18>(x, coef, cv, av, out, W1, HC, HO, stream);
    } else {
        lasry_kernel<0, 1, 64, 64, 1024, 8><<<dim3(3, 3, 256), 1024, 0, stream>>>(x, coef, cv, av, out);
        lasry_kernel<1, 3, 64, 64, 1024, 8><<<dim3(3, 3, 256), 1024, 0, stream>>>(x, coef, cv, av, out);
        lasry_kernel<2, 8, 64, 64, 1024, 4><<<dim3(3, 3, 256), 1024, 0, stream>>>(x, coef, cv, av, out);
        lasry_kernel<3, 18, 64, 48, 1024, 4><<<dim3(4, 3, 256), 1024, 0, stream>>>(x, coef, cv, av, out);
    }
}

// Round 5
// 850.017 us; speedup vs baseline: 1.1591x; 1.0984x over previous
//
#include <hip/hip_runtime.h>

// ScaleLasryLions R6: all-planar pipeline, fused-branch K1, in-place K2,
// full-H processing (no h-halving; SI3 splits on batch instead — no halo).
// closing = eroW(eroH(dilH(dilW x))), opening = dilW(dilH(eroH(eroW x)))
// (same-type separable passes commute exactly).
//   K1: x -> dilW -> W1d  AND  eroW -> W1e  (one x read, both branches)
//       planar [p][r][w], p = c*NB+bi, r in [0, HH+4SW), pitch r16(OW)
//   K2: fused H-pair per branch, IN-PLACE on W1 (block reads its whole
//       16-w column stripe to LDS before writing rows [0,HH) of same stripe)
//   K3: final W-pass both branches + blend + interleaved scatter to out
// Live workspace = W1d+W1e only (max 95.4 MB at SI2, NB=8).

constexpr int BB = 8, HH = 192, WW = 192, CHN = 32, SCST = 128;

constexpr float s2_of(int si) { // scale^2 for {0.25,0.75,1.75,3.75}
    return si == 0 ? 0.0625f : si == 1 ? 0.5625f : si == 2 ? 3.0625f : 14.0625f;
}
constexpr int cdiv_(int a, int b) { return (a + b - 1) / b; }
constexpr int r16_(int a) { return (a + 15) & ~15; }

// ---------------- K1: W-pass, both branches from one x read ----------------
template <int SI, int SW, int NB>
__launch_bounds__(256, 4) __global__
void k1_w(const float* __restrict__ x, const float* __restrict__ coef,
          float* __restrict__ W1d, float* __restrict__ W1e, int b0) {
    constexpr int L = 2 * SW + 1, WIN = WW + 4 * SW, OW = WW + 2 * SW;
    constexpr int PITCH = r16_(OW), RIN = HH + 4 * SW;
    constexpr int PIN = WIN + 1, PST = OW + 1;
    constexpr int CE = cdiv_(OW, 8);
    constexpr float S2 = s2_of(SI);
    __shared__ float sm[32 * PIN];
    const int tid = threadIdx.x;
    const int r = blockIdx.x, bi = blockIdx.y, b = b0 + bi;
    int gh = r - 2 * SW;
    gh = gh < 0 ? 0 : (gh > HH - 1 ? HH - 1 : gh);
    // load row window: lanes sweep c (128B chunks), w outer
    for (int idx = tid; idx < 32 * WIN; idx += 256) {
        int c = idx & 31, w = idx >> 5;
        int gw = w - 2 * SW;
        gw = gw < 0 ? 0 : (gw > WW - 1 ? WW - 1 : gw);
        sm[c * PIN + w] = x[((size_t)(b * HH + gh) * WW + gw) * SCST + SI * CHN + c];
    }
    __syncthreads();
    const int c = tid & 31, g = tid >> 5;
    const float km = coef[c];
    float wbuf[CE + 2 * SW];
#pragma unroll
    for (int t = 0; t < CE + 2 * SW; ++t) {
        int wi = g * CE + t;
        wi = wi < WIN ? wi : WIN - 1;
        wbuf[t] = sm[c * PIN + wi];
    }
    __syncthreads(); // all reads of sm done; safe to overwrite
    float acc[CE];
    { // dilation -> W1d
#pragma unroll
        for (int j = 0; j < L; ++j) {
            const float v = (float)(j - SW);
            const float tp = (-(v * v) / S2) * km;
#pragma unroll
            for (int o = 0; o < CE; ++o) {
                float t2 = wbuf[o + j] + tp;
                acc[o] = (j == 0) ? t2 : fmaxf(acc[o], t2);
            }
        }
#pragma unroll
        for (int o = 0; o < CE; ++o) {
            int w = g * CE + o;
            if (w < OW) sm[c * PST + w] = acc[o];
        }
    }
    __syncthreads();
    for (int idx = tid; idx < 32 * OW; idx += 256) {
        int cc = idx / OW, w = idx - cc * OW;
        W1d[((size_t)(cc * NB + bi) * RIN + r) * PITCH + w] = sm[cc * PST + w];
    }
    __syncthreads();
    { // erosion -> W1e
#pragma unroll
        for (int j = 0; j < L; ++j) {
            const float v = (float)(j - SW);
            const float tp = (-(v * v) / S2) * km;
#pragma unroll
            for (int o = 0; o < CE; ++o) {
                float t2 = wbuf[o + j] - tp;
                acc[o] = (j == 0) ? t2 : fminf(acc[o], t2);
            }
        }
#pragma unroll
        for (int o = 0; o < CE; ++o) {
            int w = g * CE + o;
            if (w < OW) sm[c * PST + w] = acc[o];
        }
    }
    __syncthreads();
    for (int idx = tid; idx < 32 * OW; idx += 256) {
        int cc = idx / OW, w = idx - cc * OW;
        W1e[((size_t)(cc * NB + bi) * RIN + r) * PITCH + w] = sm[cc * PST + w];
    }
}

// ---------------- K2: fused H-pass pair, IN-PLACE, 16-w column stripes ------
// BR=0 (closing, on W1d): dilH(+k,max) then eroH(-kc,min)
// BR=1 (opening, on W1e): eroH(-k,min) then dilH(+kc,max)
// Reads rows [0,RIN) of stripe, writes rows [0,HH) of SAME stripe (safe:
// whole stripe is in LDS before any global write).
template <int SI, int SW, int NB, int BR>
__launch_bounds__(256, 4) __global__
void k2_h(float* __restrict__ P, const float* __restrict__ coef,
          const float* __restrict__ cv) {
    constexpr int L = 2 * SW + 1, OW = WW + 2 * SW, PITCH = r16_(OW);
    constexpr int RIN = HH + 4 * SW, RD = HH + 2 * SW;
    constexpr int CH1 = cdiv_(RD, 16), CH2 = HH / 16; // 16 row-groups
    constexpr float S2 = s2_of(SI);
    __shared__ float tin[RIN * 17];
    __shared__ float tdil[RD * 17];
    const int tid = threadIdx.x;
    const int st = blockIdx.x, p = blockIdx.y, c = p / NB;
    const float k1 = coef[c], k2 = coef[c] * cv[c];
    float* wrow = P + (size_t)p * RIN * PITCH + st * 16;
    for (int idx = tid; idx < RIN * 16; idx += 256) {
        int r = idx >> 4, w = idx & 15;
        tin[r * 17 + w] = wrow[(size_t)r * PITCH + w];
    }
    __syncthreads();
    const int w = tid & 15, rg = tid >> 4;
    { // phase 1: taps k
        float wbuf[CH1 + 2 * SW];
#pragma unroll
        for (int t = 0; t < CH1 + 2 * SW; ++t) {
            int ri = rg * CH1 + t;
            ri = ri < RIN ? ri : RIN - 1;
            wbuf[t] = tin[ri * 17 + w];
        }
        float acc[CH1];
#pragma unroll
        for (int j = 0; j < L; ++j) {
            const float v = (float)(j - SW);
            const float tp = (-(v * v) / S2) * k1;
#pragma unroll
            for (int o = 0; o < CH1; ++o) {
                float t2 = BR ? wbuf[o + j] - tp : wbuf[o + j] + tp;
                acc[o] = (j == 0) ? t2 : (BR ? fminf(acc[o], t2) : fmaxf(acc[o], t2));
            }
        }
#pragma unroll
        for (int o = 0; o < CH1; ++o) {
            int d = rg * CH1 + o;
            if (d < RD) tdil[d * 17 + w] = acc[o];
        }
    }
    __syncthreads();
    { // phase 2: taps kc, opposite op; write rows [0,HH) in place
        float wbuf[CH2 + 2 * SW];
#pragma unroll
        for (int t = 0; t < CH2 + 2 * SW; ++t) wbuf[t] = tdil[(rg * CH2 + t) * 17 + w];
        float acc[CH2];
#pragma unroll
        for (int j = 0; j < L; ++j) {
            const float v = (float)(j - SW);
            const float tp = (-(v * v) / S2) * k2;
#pragma unroll
            for (int o = 0; o < CH2; ++o) {
                float t2 = BR ? wbuf[o + j] + tp : wbuf[o + j] - tp;
                acc[o] = (j == 0) ? t2 : (BR ? fmaxf(acc[o], t2) : fminf(acc[o], t2));
            }
        }
#pragma unroll
        for (int o = 0; o < CH2; ++o) wrow[(size_t)(rg * CH2 + o) * PITCH + w] = acc[o];
    }
}

// ---------------- K3: final W-pass + blend + interleaved scatter ------------
template <int SI, int SW, int NB>
__launch_bounds__(256, 4) __global__
void k3_blend(const float* __restrict__ HC, const float* __restrict__ HO,
              const float* __restrict__ coef, const float* __restrict__ cv,
              const float* __restrict__ ain, float* __restrict__ out, int b0) {
    constexpr int L = 2 * SW + 1, OW = WW + 2 * SW, PITCH = r16_(OW), PB = OW + 1;
    constexpr int RIN = HH + 4 * SW;
    constexpr float S2 = s2_of(SI);
    __shared__ float sm[32 * PB];
    const int tid = threadIdx.x;
    const int hr = blockIdx.x, bi = blockIdx.y, b = b0 + bi;
    const int c = tid & 31, g = tid >> 5;
    const float kc = coef[c] * cv[c], av = ain[c];

    // ---- closing tail: erosion over HC rows ----
    for (int idx = tid; idx < 32 * OW; idx += 256) {
        int cc = idx / OW, w2 = idx - cc * OW;
        sm[cc * PB + w2] = HC[((size_t)(cc * NB + bi) * RIN + hr) * PITCH + w2];
    }
    __syncthreads();
    float xcv[24];
#pragma unroll
    for (int ch = 0; ch < 2; ++ch) {
        const int base = g * 24 + ch * 12;
        float wbuf[12 + 2 * SW];
#pragma unroll
        for (int t = 0; t < 12 + 2 * SW; ++t) wbuf[t] = sm[c * PB + base + t];
#pragma unroll
        for (int j = 0; j < L; ++j) {
            const float v = (float)(j - SW);
            const float tp = (-(v * v) / S2) * kc;
#pragma unroll
            for (int o = 0; o < 12; ++o) {
                float t2 = wbuf[o + j] - tp; // erosion
                float& d = xcv[ch * 12 + o];
                d = (j == 0) ? t2 : fminf(d, t2);
            }
        }
    }
    __syncthreads();
    // ---- opening tail: dilation over HO rows, blend ----
    for (int idx = tid; idx < 32 * OW; idx += 256) {
        int cc = idx / OW, w2 = idx - cc * OW;
        sm[cc * PB + w2] = HO[((size_t)(cc * NB + bi) * RIN + hr) * PITCH + w2];
    }
    __syncthreads();
    float bl[24];
#pragma unroll
    for (int ch = 0; ch < 2; ++ch) {
        const int base = g * 24 + ch * 12;
        float wbuf[12 + 2 * SW];
#pragma unroll
        for (int t = 0; t < 12 + 2 * SW; ++t) wbuf[t] = sm[c * PB + base + t];
        float xo[12];
#pragma unroll
        for (int j = 0; j < L; ++j) {
            const float v = (float)(j - SW);
            const float tp = (-(v * v) / S2) * kc;
#pragma unroll
            for (int o = 0; o < 12; ++o) {
                float t2 = wbuf[o + j] + tp; // dilation
                xo[o] = (j == 0) ? t2 : fmaxf(xo[o], t2);
            }
        }
#pragma unroll
        for (int o = 0; o < 12; ++o)
            bl[ch * 12 + o] = av * xcv[ch * 12 + o] + (1.0f - av) * xo[o];
    }
    __syncthreads();
#pragma unroll
    for (int o = 0; o < 24; ++o) sm[c * 193 + g * 24 + o] = bl[o];
    __syncthreads();
    for (int idx = tid; idx < WW * 32; idx += 256) {
        int w2 = idx >> 5, cc = idx & 31;
        out[((size_t)(b * HH + hr) * WW + w2) * SCST + SI * CHN + cc] = sm[cc * 193 + w2];
    }
}

// ---------------- Fallback: fused kernel (used if ws too small) ----------------
constexpr int r4_(int a) { return (a + 3) & ~3; }
constexpr int pickNH(int R, int C, int NT) {
    for (int nh = 1; nh <= R; ++nh)
        if (cdiv_(R, nh) * C <= NT) return nh;
    return R;
}
template <int L, int SW, int SI, bool DIL, int NH, int R, int PIT>
__device__ __forceinline__ void pass_compute_si(const float* __restrict__ in, int r0, int c,
                                                float kmul, float (&acc)[NH]) {
    constexpr float S2 = s2_of(SI);
    float wb[NH + L - 1];
#pragma unroll
    for (int t = 0; t < NH + L - 1; ++t) {
        int rr = r0 + t;
        if (rr > R + L - 2) rr = R + L - 2;
        wb[t] = in[rr * PIT + c];
    }
#pragma unroll
    for (int j = 0; j < L; ++j) {
        float v = (float)(j - SW);
        float tp = (-(v * v) / S2) * kmul;
#pragma unroll
        for (int o = 0; o < NH; ++o) {
            float t = DIL ? wb[o + j] + tp : wb[o + j] - tp;
            if (j == 0) acc[o] = t;
            else acc[o] = DIL ? fmaxf(acc[o], t) : fminf(acc[o], t);
        }
    }
}
template <int L, int SW, int SI, bool DIL, int NH, int R, int C, int PIT, int POUT, int NT>
__device__ __forceinline__ void pass_lds(const float* __restrict__ in, float* __restrict__ outT,
                                         float kmul, int tid) {
    constexpr int nseg = cdiv_(R, NH);
    for (int item = tid; item < nseg * C; item += NT) {
        int c = item % C, r0 = (item / C) * NH;
        float acc[NH];
        pass_compute_si<L, SW, SI, DIL, NH, R, PIT>(in, r0, c, kmul, acc);
#pragma unroll
        for (int o = 0; o < NH; ++o)
            if (r0 + o < R) outT[c * POUT + (r0 + o)] = acc[o];
    }
}
template <int SI, int SW, int TH, int TW, int NT, int MW>
__launch_bounds__(NT, MW) __global__
void lasry_kernel(const float* __restrict__ x, const float* __restrict__ coef,
                  const float* __restrict__ cin, const float* __restrict__ ain,
                  float* __restrict__ out) {
    constexpr int L = 2 * SW + 1;
    constexpr int IH = TH + 4 * SW, IW = TW + 4 * SW;
    constexpr int R1 = TH + 2 * SW, C1 = IW;
    constexpr int R2 = TW + 2 * SW, C2 = R1;
    constexpr int R3 = TH,          C3 = R2;
    constexpr int R4 = TW,          C4 = R3;
    constexpr int PIN = IW, PA = r4_(R1), PB = r4_(R2), PA2 = r4_(R3);
    constexpr int NH1 = pickNH(R1, C1, NT), NH2 = pickNH(R2, C2, NT);
    constexpr int NH3 = pickNH(R3, C3, NT), NH4 = pickNH(R4, C4, NT);
    __shared__ float smem[IH * PIN + C1 * PA + C2 * PB];
    float* bufIn = smem;
    float* A = smem + IH * PIN;
    float* B = A + C1 * PA;
    float* A2 = A;
    const int tid = threadIdx.x;
    const int b = blockIdx.z >> 5, ch = blockIdx.z & 31;
    const int h0 = blockIdx.y * TH, w0 = blockIdx.x * TW;
    const float kmul = coef[ch];
    const float kcmul = kmul * cin[ch];
    const float av = ain[ch];
    const float* xb = x + (size_t)(b * HH * WW) * SCST + SI * CHN + ch;
    constexpr int NLOAD = cdiv_(IH * IW, NT);
#pragma unroll
    for (int t = 0; t < NLOAD; ++t) {
        int idx = tid + t * NT;
        if (idx < IH * IW) {
            int r = idx / IW, c = idx - r * IW;
            int gh = min(max(h0 + r - 2 * SW, 0), HH - 1);
            int gw = min(max(w0 + c - 2 * SW, 0), WW - 1);
            bufIn[r * PIN + c] = xb[(size_t)(gh * WW + gw) * SCST];
        }
    }
    __syncthreads();
    const int c4 = tid % C4;
    const int r04 = (tid / C4) * NH4;
    const bool act4 = tid < cdiv_(R4, NH4) * C4;
    float xcv[NH4];
    pass_lds<L, SW, SI, true,  NH1, R1, C1, PIN, PA,  NT>(bufIn, A, kmul, tid);  __syncthreads();
    pass_lds<L, SW, SI, true,  NH2, R2, C2, PA,  PB,  NT>(A,     B, kmul, tid);  __syncthreads();
    pass_lds<L, SW, SI, false, NH3, R3, C3, PB,  PA2, NT>(B,    A2, kcmul, tid); __syncthreads();
    if (act4) pass_compute_si<L, SW, SI, false, NH4, R4, PA2>(A2, r04, c4, kcmul, xcv);
    __syncthreads();
    pass_lds<L, SW, SI, false, NH1, R1, C1, PIN, PA,  NT>(bufIn, A, kmul, tid);  __syncthreads();
    pass_lds<L, SW, SI, false, NH2, R2, C2, PA,  PB,  NT>(A,     B, kmul, tid);  __syncthreads();
    pass_lds<L, SW, SI, true,  NH3, R3, C3, PB,  PA2, NT>(B,    A2, kcmul, tid); __syncthreads();
    if (act4) {
        float xov[NH4];
        pass_compute_si<L, SW, SI, true, NH4, R4, PA2>(A2, r04, c4, kcmul, xov);
        const int h = h0 + c4;
        float* ob = out + ((size_t)(b * HH + h) * WW) * SCST + SI * CHN + ch;
#pragma unroll
        for (int o = 0; o < NH4; ++o) {
            int w = w0 + r04 + o;
            if (r04 + o < R4 && w < WW) ob[(size_t)w * SCST] = av * xcv[o] + (1.0f - av) * xov[o];
        }
    }
}

// ---------------- host ----------------
template <int SI, int SW, int NB>
static void run_scale(const float* x, const float* coef, const float* cv, const float* av,
                      float* out, float* ws, int b0, hipStream_t s) {
    constexpr int OW = WW + 2 * SW, PITCH = r16_(OW);
    constexpr int RIN = HH + 4 * SW, NST = PITCH / 16;
    constexpr size_t W1SZ = (size_t)RIN * PITCH * CHN * NB;
    float* W1d = ws;
    float* W1e = ws + W1SZ;
    k1_w<SI, SW, NB><<<dim3(RIN, NB), 256, 0, s>>>(x, coef, W1d, W1e, b0);
    k2_h<SI, SW, NB, 0><<<dim3(NST, CHN * NB), 256, 0, s>>>(W1d, coef, cv);
    k2_h<SI, SW, NB, 1><<<dim3(NST, CHN * NB), 256, 0, s>>>(W1e, coef, cv);
    k3_blend<SI, SW, NB><<<dim3(HH, NB), 256, 0, s>>>(W1d, W1e, coef, cv, av, out, b0);
}

extern "C" void kernel_launch(void* const* d_in, const int* in_sizes, int n_in,
                              void* d_out, int out_size, void* d_ws, size_t ws_size,
                              hipStream_t stream) {
    const float* x    = (const float*)d_in[0];
    const float* coef = (const float*)d_in[1];
    const float* cv   = (const float*)d_in[2];
    const float* av   = (const float*)d_in[3];
    float* out = (float*)d_out;
    (void)in_sizes; (void)n_in; (void)out_size;

    // peak live = 2 * RIN * PITCH * CHN * NB floats; max at SI2 (NB=8):
    // 2 * 224 * 208 * 32 * 8 * 4B = 95,420,416 B
    constexpr size_t NEED = 2ull * 224 * 208 * CHN * 8 * sizeof(float);

    if (ws_size >= NEED) {
        float* ws = (float*)d_ws;
        run_scale<0, 1, BB>(x, coef, cv, av, out, ws, 0, stream);
        run_scale<1, 3, BB>(x, coef, cv, av, out, ws, 0, stream);
        run_scale<2, 8, BB>(x, coef, cv, av, out, ws, 0, stream);
        run_scale<3, 18, 4>(x, coef, cv, av, out, ws, 0, stream);
        run_scale<3, 18, 4>(x, coef, cv, av, out, ws, 4, stream);
    } else {
        lasry_kernel<0, 1, 64, 64, 1024, 8><<<dim3(3, 3, 256), 1024, 0, stream>>>(x, coef, cv, av, out);
        lasry_kernel<1, 3, 64, 64, 1024, 8><<<dim3(3, 3, 256), 1024, 0, stream>>>(x, coef, cv, av, out);
        lasry_kernel<2, 8, 64, 64, 1024, 4><<<dim3(3, 3, 256), 1024, 0, stream>>>(x, coef, cv, av, out);
        lasry_kernel<3, 18, 64, 48, 1024, 4><<<dim3(4, 3, 256), 1024, 0, stream>>>(x, coef, cv, av, out);
    }
}

// Round 6
// 720.816 us; speedup vs baseline: 1.3669x; 1.1792x over previous
//
#include <hip/hip_runtime.h>
#include <hip/hip_fp16.h>

// ScaleLasryLions R7: all-planar pipeline, fp16 intermediates, merged-branch
// K2 (negation trick), NB=8 for all scales. 12 dispatches total.
// closing = eroW(eroH(dilH(dilW x))), opening = dilW(dilH(eroH(eroW x)))
// (same-type separable passes commute exactly).
//   K1: x -> dilW -> W1d AND eroW -> W1e (one x read), planar fp16
//       [p][r][w], p = c*NB+bi, r in [0,HH+4SW), PITCH mult-of-32 (64B rows)
//   K2: fused H-pair, IN-PLACE, grid.z picks branch; ero == -dil(-x) so both
//       branches run identical dil->ero code on sign-flipped data
//   K3: final W-pass both branches + blend + interleaved scatter
// Live workspace = one scale's W1 pair (max 69.2 MB at SI3, L3-resident).

constexpr int BB = 8, HH = 192, WW = 192, CHN = 32, SCST = 128;

constexpr float s2_of(int si) { // scale^2 for {0.25,0.75,1.75,3.75}
    return si == 0 ? 0.0625f : si == 1 ? 0.5625f : si == 2 ? 3.0625f : 14.0625f;
}
constexpr int cdiv_(int a, int b) { return (a + b - 1) / b; }
constexpr int r32_(int a) { return (a + 31) & ~31; }

// ---------------- K1: W-pass, both branches from one x read ----------------
template <int SI, int SW, int NB>
__launch_bounds__(256, 4) __global__
void k1_w(const float* __restrict__ x, const float* __restrict__ coef,
          __half* __restrict__ W1d, __half* __restrict__ W1e) {
    constexpr int L = 2 * SW + 1, WIN = WW + 4 * SW, OW = WW + 2 * SW;
    constexpr int PITCH = r32_(OW), RIN = HH + 4 * SW;
    constexpr int PIN = WIN + 1, PST = OW + 1;
    constexpr int CE = cdiv_(OW, 8), OW2 = OW / 2;
    constexpr float S2 = s2_of(SI);
    __shared__ float sm[32 * PIN];
    const int tid = threadIdx.x;
    const int r = blockIdx.x, bi = blockIdx.y;
    int gh = r - 2 * SW;
    gh = gh < 0 ? 0 : (gh > HH - 1 ? HH - 1 : gh);
    for (int idx = tid; idx < 32 * WIN; idx += 256) {
        int c = idx & 31, w = idx >> 5;
        int gw = w - 2 * SW;
        gw = gw < 0 ? 0 : (gw > WW - 1 ? WW - 1 : gw);
        sm[c * PIN + w] = x[((size_t)(bi * HH + gh) * WW + gw) * SCST + SI * CHN + c];
    }
    __syncthreads();
    const int c = tid & 31, g = tid >> 5;
    const float km = coef[c];
    float wbuf[CE + 2 * SW];
#pragma unroll
    for (int t = 0; t < CE + 2 * SW; ++t) {
        int wi = g * CE + t;
        wi = wi < WIN ? wi : WIN - 1;
        wbuf[t] = sm[c * PIN + wi];
    }
    __syncthreads(); // all reads of sm done; safe to overwrite
    float acc[CE];
    { // dilation -> W1d
#pragma unroll
        for (int j = 0; j < L; ++j) {
            const float v = (float)(j - SW);
            const float tp = (-(v * v) / S2) * km;
#pragma unroll
            for (int o = 0; o < CE; ++o) {
                float t2 = wbuf[o + j] + tp;
                acc[o] = (j == 0) ? t2 : fmaxf(acc[o], t2);
            }
        }
#pragma unroll
        for (int o = 0; o < CE; ++o) {
            int w = g * CE + o;
            if (w < OW) sm[c * PST + w] = acc[o];
        }
    }
    __syncthreads();
    for (int idx = tid; idx < 32 * OW2; idx += 256) {
        int cc = idx / OW2, wp = idx - cc * OW2;
        __half2 hv = __floats2half2_rn(sm[cc * PST + 2 * wp], sm[cc * PST + 2 * wp + 1]);
        *(__half2*)&W1d[((size_t)(cc * NB + bi) * RIN + r) * PITCH + 2 * wp] = hv;
    }
    __syncthreads();
    { // erosion -> W1e
#pragma unroll
        for (int j = 0; j < L; ++j) {
            const float v = (float)(j - SW);
            const float tp = (-(v * v) / S2) * km;
#pragma unroll
            for (int o = 0; o < CE; ++o) {
                float t2 = wbuf[o + j] - tp;
                acc[o] = (j == 0) ? t2 : fminf(acc[o], t2);
            }
        }
#pragma unroll
        for (int o = 0; o < CE; ++o) {
            int w = g * CE + o;
            if (w < OW) sm[c * PST + w] = acc[o];
        }
    }
    __syncthreads();
    for (int idx = tid; idx < 32 * OW2; idx += 256) {
        int cc = idx / OW2, wp = idx - cc * OW2;
        __half2 hv = __floats2half2_rn(sm[cc * PST + 2 * wp], sm[cc * PST + 2 * wp + 1]);
        *(__half2*)&W1e[((size_t)(cc * NB + bi) * RIN + r) * PITCH + 2 * wp] = hv;
    }
}

// ---------------- K2: fused H-pair, IN-PLACE, both branches via grid.z ------
// z=0 (closing, W1d): dilH(+k,max) then eroH(-kc,min)
// z=1 (opening, W1e): eroH == -dilH(-x); load *s, run dil->ero, store *s.
template <int SI, int SW, int NB>
__launch_bounds__(256, 4) __global__
void k2_h(__half* __restrict__ W1d, __half* __restrict__ W1e,
          const float* __restrict__ coef, const float* __restrict__ cv) {
    constexpr int L = 2 * SW + 1, OW = WW + 2 * SW, PITCH = r32_(OW);
    constexpr int RIN = HH + 4 * SW, RD = HH + 2 * SW;
    constexpr int CH1 = cdiv_(RD, 16), CH2 = HH / 16;
    constexpr float S2 = s2_of(SI);
    __shared__ float tin[RIN * 17];
    __shared__ float tdil[RD * 17];
    const int tid = threadIdx.x;
    const int st = blockIdx.x, p = blockIdx.y, z = blockIdx.z;
    const int c = p / NB;
    const float s = z ? -1.0f : 1.0f;
    const float k1 = coef[c], k2 = coef[c] * cv[c];
    __half* wrow = (z ? W1e : W1d) + (size_t)p * RIN * PITCH + st * 16;
    for (int idx = tid; idx < RIN * 8; idx += 256) {
        int r = idx >> 3, wp = idx & 7;
        float2 f = __half22float2(*(const __half2*)&wrow[(size_t)r * PITCH + 2 * wp]);
        tin[r * 17 + 2 * wp] = s * f.x;
        tin[r * 17 + 2 * wp + 1] = s * f.y;
    }
    __syncthreads();
    const int w = tid & 15, rg = tid >> 4;
    { // phase 1: dilation, taps k
        float wbuf[CH1 + 2 * SW];
#pragma unroll
        for (int t = 0; t < CH1 + 2 * SW; ++t) {
            int ri = rg * CH1 + t;
            ri = ri < RIN ? ri : RIN - 1;
            wbuf[t] = tin[ri * 17 + w];
        }
        float acc[CH1];
#pragma unroll
        for (int j = 0; j < L; ++j) {
            const float v = (float)(j - SW);
            const float tp = (-(v * v) / S2) * k1;
#pragma unroll
            for (int o = 0; o < CH1; ++o) {
                float t2 = wbuf[o + j] + tp;
                acc[o] = (j == 0) ? t2 : fmaxf(acc[o], t2);
            }
        }
#pragma unroll
        for (int o = 0; o < CH1; ++o) {
            int d = rg * CH1 + o;
            if (d < RD) tdil[d * 17 + w] = acc[o];
        }
    }
    __syncthreads();
    { // phase 2: erosion, taps kc; write rows [0,HH) in place
        float wbuf[CH2 + 2 * SW];
#pragma unroll
        for (int t = 0; t < CH2 + 2 * SW; ++t) wbuf[t] = tdil[(rg * CH2 + t) * 17 + w];
        float acc[CH2];
#pragma unroll
        for (int j = 0; j < L; ++j) {
            const float v = (float)(j - SW);
            const float tp = (-(v * v) / S2) * k2;
#pragma unroll
            for (int o = 0; o < CH2; ++o) {
                float t2 = wbuf[o + j] - tp;
                acc[o] = (j == 0) ? t2 : fminf(acc[o], t2);
            }
        }
#pragma unroll
        for (int o = 0; o < CH2; ++o)
            wrow[(size_t)(rg * CH2 + o) * PITCH + w] = __float2half(s * acc[o]);
    }
}

// ---------------- K3: final W-pass + blend + interleaved scatter ------------
template <int SI, int SW, int NB>
__launch_bounds__(256, 4) __global__
void k3_blend(const __half* __restrict__ HC, const __half* __restrict__ HO,
              const float* __restrict__ coef, const float* __restrict__ cv,
              const float* __restrict__ ain, float* __restrict__ out) {
    constexpr int L = 2 * SW + 1, OW = WW + 2 * SW, PITCH = r32_(OW), PB = OW + 1;
    constexpr int RIN = HH + 4 * SW, OW2 = OW / 2;
    constexpr float S2 = s2_of(SI);
    __shared__ float sm[32 * PB];
    const int tid = threadIdx.x;
    const int hr = blockIdx.x, bi = blockIdx.y;
    const int c = tid & 31, g = tid >> 5;
    const float kc = coef[c] * cv[c], av = ain[c];

    // ---- closing tail: erosion over HC row ----
    for (int idx = tid; idx < 32 * OW2; idx += 256) {
        int cc = idx / OW2, wp = idx - cc * OW2;
        float2 f = __half22float2(*(const __half2*)&HC[((size_t)(cc * NB + bi) * RIN + hr) * PITCH + 2 * wp]);
        sm[cc * PB + 2 * wp] = f.x;
        sm[cc * PB + 2 * wp + 1] = f.y;
    }
    __syncthreads();
    float xcv[24];
#pragma unroll
    for (int ch = 0; ch < 2; ++ch) {
        const int base = g * 24 + ch * 12;
        float wbuf[12 + 2 * SW];
#pragma unroll
        for (int t = 0; t < 12 + 2 * SW; ++t) wbuf[t] = sm[c * PB + base + t];
#pragma unroll
        for (int j = 0; j < L; ++j) {
            const float v = (float)(j - SW);
            const float tp = (-(v * v) / S2) * kc;
#pragma unroll
            for (int o = 0; o < 12; ++o) {
                float t2 = wbuf[o + j] - tp; // erosion
                float& d = xcv[ch * 12 + o];
                d = (j == 0) ? t2 : fminf(d, t2);
            }
        }
    }
    __syncthreads();
    // ---- opening tail: dilation over HO row, blend ----
    for (int idx = tid; idx < 32 * OW2; idx += 256) {
        int cc = idx / OW2, wp = idx - cc * OW2;
        float2 f = __half22float2(*(const __half2*)&HO[((size_t)(cc * NB + bi) * RIN + hr) * PITCH + 2 * wp]);
        sm[cc * PB + 2 * wp] = f.x;
        sm[cc * PB + 2 * wp + 1] = f.y;
    }
    __syncthreads();
    float bl[24];
#pragma unroll
    for (int ch = 0; ch < 2; ++ch) {
        const int base = g * 24 + ch * 12;
        float wbuf[12 + 2 * SW];
#pragma unroll
        for (int t = 0; t < 12 + 2 * SW; ++t) wbuf[t] = sm[c * PB + base + t];
        float xo[12];
#pragma unroll
        for (int j = 0; j < L; ++j) {
            const float v = (float)(j - SW);
            const float tp = (-(v * v) / S2) * kc;
#pragma unroll
            for (int o = 0; o < 12; ++o) {
                float t2 = wbuf[o + j] + tp; // dilation
                xo[o] = (j == 0) ? t2 : fmaxf(xo[o], t2);
            }
        }
#pragma unroll
        for (int o = 0; o < 12; ++o)
            bl[ch * 12 + o] = av * xcv[ch * 12 + o] + (1.0f - av) * xo[o];
    }
    __syncthreads();
#pragma unroll
    for (int o = 0; o < 24; ++o) sm[c * 193 + g * 24 + o] = bl[o];
    __syncthreads();
    for (int idx = tid; idx < WW * 32; idx += 256) {
        int w2 = idx >> 5, cc = idx & 31;
        out[((size_t)(bi * HH + hr) * WW + w2) * SCST + SI * CHN + cc] = sm[cc * 193 + w2];
    }
}

// ---------------- Fallback: fused kernel (used if ws too small) ----------------
constexpr int r4_(int a) { return (a + 3) & ~3; }
constexpr int pickNH(int R, int C, int NT) {
    for (int nh = 1; nh <= R; ++nh)
        if (cdiv_(R, nh) * C <= NT) return nh;
    return R;
}
template <int L, int SW, int SI, bool DIL, int NH, int R, int PIT>
__device__ __forceinline__ void pass_compute_si(const float* __restrict__ in, int r0, int c,
                                                float kmul, float (&acc)[NH]) {
    constexpr float S2 = s2_of(SI);
    float wb[NH + L - 1];
#pragma unroll
    for (int t = 0; t < NH + L - 1; ++t) {
        int rr = r0 + t;
        if (rr > R + L - 2) rr = R + L - 2;
        wb[t] = in[rr * PIT + c];
    }
#pragma unroll
    for (int j = 0; j < L; ++j) {
        float v = (float)(j - SW);
        float tp = (-(v * v) / S2) * kmul;
#pragma unroll
        for (int o = 0; o < NH; ++o) {
            float t = DIL ? wb[o + j] + tp : wb[o + j] - tp;
            if (j == 0) acc[o] = t;
            else acc[o] = DIL ? fmaxf(acc[o], t) : fminf(acc[o], t);
        }
    }
}
template <int L, int SW, int SI, bool DIL, int NH, int R, int C, int PIT, int POUT, int NT>
__device__ __forceinline__ void pass_lds(const float* __restrict__ in, float* __restrict__ outT,
                                         float kmul, int tid) {
    constexpr int nseg = cdiv_(R, NH);
    for (int item = tid; item < nseg * C; item += NT) {
        int c = item % C, r0 = (item / C) * NH;
        float acc[NH];
        pass_compute_si<L, SW, SI, DIL, NH, R, PIT>(in, r0, c, kmul, acc);
#pragma unroll
        for (int o = 0; o < NH; ++o)
            if (r0 + o < R) outT[c * POUT + (r0 + o)] = acc[o];
    }
}
template <int SI, int SW, int TH, int TW, int NT, int MW>
__launch_bounds__(NT, MW) __global__
void lasry_kernel(const float* __restrict__ x, const float* __restrict__ coef,
                  const float* __restrict__ cin, const float* __restrict__ ain,
                  float* __restrict__ out) {
    constexpr int L = 2 * SW + 1;
    constexpr int IH = TH + 4 * SW, IW = TW + 4 * SW;
    constexpr int R1 = TH + 2 * SW, C1 = IW;
    constexpr int R2 = TW + 2 * SW, C2 = R1;
    constexpr int R3 = TH,          C3 = R2;
    constexpr int R4 = TW,          C4 = R3;
    constexpr int PIN = IW, PA = r4_(R1), PB = r4_(R2), PA2 = r4_(R3);
    constexpr int NH1 = pickNH(R1, C1, NT), NH2 = pickNH(R2, C2, NT);
    constexpr int NH3 = pickNH(R3, C3, NT), NH4 = pickNH(R4, C4, NT);
    __shared__ float smem[IH * PIN + C1 * PA + C2 * PB];
    float* bufIn = smem;
    float* A = smem + IH * PIN;
    float* B = A + C1 * PA;
    float* A2 = A;
    const int tid = threadIdx.x;
    const int b = blockIdx.z >> 5, ch = blockIdx.z & 31;
    const int h0 = blockIdx.y * TH, w0 = blockIdx.x * TW;
    const float kmul = coef[ch];
    const float kcmul = kmul * cin[ch];
    const float av = ain[ch];
    const float* xb = x + (size_t)(b * HH * WW) * SCST + SI * CHN + ch;
    constexpr int NLOAD = cdiv_(IH * IW, NT);
#pragma unroll
    for (int t = 0; t < NLOAD; ++t) {
        int idx = tid + t * NT;
        if (idx < IH * IW) {
            int r = idx / IW, c = idx - r * IW;
            int gh = min(max(h0 + r - 2 * SW, 0), HH - 1);
            int gw = min(max(w0 + c - 2 * SW, 0), WW - 1);
            bufIn[r * PIN + c] = xb[(size_t)(gh * WW + gw) * SCST];
        }
    }
    __syncthreads();
    const int c4 = tid % C4;
    const int r04 = (tid / C4) * NH4;
    const bool act4 = tid < cdiv_(R4, NH4) * C4;
    float xcv[NH4];
    pass_lds<L, SW, SI, true,  NH1, R1, C1, PIN, PA,  NT>(bufIn, A, kmul, tid);  __syncthreads();
    pass_lds<L, SW, SI, true,  NH2, R2, C2, PA,  PB,  NT>(A,     B, kmul, tid);  __syncthreads();
    pass_lds<L, SW, SI, false, NH3, R3, C3, PB,  PA2, NT>(B,    A2, kcmul, tid); __syncthreads();
    if (act4) pass_compute_si<L, SW, SI, false, NH4, R4, PA2>(A2, r04, c4, kcmul, xcv);
    __syncthreads();
    pass_lds<L, SW, SI, false, NH1, R1, C1, PIN, PA,  NT>(bufIn, A, kmul, tid);  __syncthreads();
    pass_lds<L, SW, SI, false, NH2, R2, C2, PA,  PB,  NT>(A,     B, kmul, tid);  __syncthreads();
    pass_lds<L, SW, SI, true,  NH3, R3, C3, PB,  PA2, NT>(B,    A2, kcmul, tid); __syncthreads();
    if (act4) {
        float xov[NH4];
        pass_compute_si<L, SW, SI, true, NH4, R4, PA2>(A2, r04, c4, kcmul, xov);
        const int h = h0 + c4;
        float* ob = out + ((size_t)(b * HH + h) * WW) * SCST + SI * CHN + ch;
#pragma unroll
        for (int o = 0; o < NH4; ++o) {
            int w = w0 + r04 + o;
            if (r04 + o < R4 && w < WW) ob[(size_t)w * SCST] = av * xcv[o] + (1.0f - av) * xov[o];
        }
    }
}

// ---------------- host ----------------
template <int SI, int SW>
static void run_scale(const float* x, const float* coef, const float* cv, const float* av,
                      float* out, __half* ws, hipStream_t s) {
    constexpr int NB = BB;
    constexpr int OW = WW + 2 * SW, PITCH = r32_(OW);
    constexpr int RIN = HH + 4 * SW, NST = cdiv_(OW, 16);
    constexpr size_t W1SZ = (size_t)RIN * PITCH * CHN * NB;
    __half* W1d = ws;
    __half* W1e = ws + W1SZ;
    k1_w<SI, SW, NB><<<dim3(RIN, NB), 256, 0, s>>>(x, coef, W1d, W1e);
    k2_h<SI, SW, NB><<<dim3(NST, CHN * NB, 2), 256, 0, s>>>(W1d, W1e, coef, cv);
    k3_blend<SI, SW, NB><<<dim3(HH, NB), 256, 0, s>>>(W1d, W1e, coef, cv, av, out);
}

extern "C" void kernel_launch(void* const* d_in, const int* in_sizes, int n_in,
                              void* d_out, int out_size, void* d_ws, size_t ws_size,
                              hipStream_t stream) {
    const float* x    = (const float*)d_in[0];
    const float* coef = (const float*)d_in[1];
    const float* cv   = (const float*)d_in[2];
    const float* av   = (const float*)d_in[3];
    float* out = (float*)d_out;
    (void)in_sizes; (void)n_in; (void)out_size;

    // peak live pair (SI3): 2 * 264 * 256 * 32 * 8 * 2B = 69,206,016 B
    constexpr size_t NEED = 2ull * 264 * 256 * CHN * BB * sizeof(__half);

    if (ws_size >= NEED) {
        __half* ws = (__half*)d_ws;
        run_scale<0, 1>(x, coef, cv, av, out, ws, stream);
        run_scale<1, 3>(x, coef, cv, av, out, ws, stream);
        run_scale<2, 8>(x, coef, cv, av, out, ws, stream);
        run_scale<3, 18>(x, coef, cv, av, out, ws, stream);
    } else {
        lasry_kernel<0, 1, 64, 64, 1024, 8><<<dim3(3, 3, 256), 1024, 0, stream>>>(x, coef, cv, av, out);
        lasry_kernel<1, 3, 64, 64, 1024, 8><<<dim3(3, 3, 256), 1024, 0, stream>>>(x, coef, cv, av, out);
        lasry_kernel<2, 8, 64, 64, 1024, 4><<<dim3(3, 3, 256), 1024, 0, stream>>>(x, coef, cv, av, out);
        lasry_kernel<3, 18, 64, 48, 1024, 4><<<dim3(4, 3, 256), 1024, 0, stream>>>(x, coef, cv, av, out);
    }
}